// Round 1
// baseline (702.814 us; speedup 1.0000x reference)
//
#include <hip/hip_runtime.h>
#include <hip/hip_bf16.h>
#include <math.h>

#define LAYERS 32
#define H      1024
#define H3     3072
#define NHEADS 16
#define HDIM   64
#define FF     2048
#define BATCH  2
#define SEQ    2048
#define EPSF   1e-6f

__device__ __forceinline__ float wredSum(float v) {
#pragma unroll
  for (int m = 32; m >= 1; m >>= 1) v += __shfl_xor(v, m, 64);
  return v;
}
__device__ __forceinline__ float wredMax(float v) {
#pragma unroll
  for (int m = 32; m >= 1; m >>= 1) v = fmaxf(v, __shfl_xor(v, m, 64));
  return v;
}
__device__ __forceinline__ float gelu_t(float x) {
  return 0.5f * x * (1.0f + tanhf(0.7978845608028654f * (x + 0.044715f * x * x * x)));
}

// ---------------------------------------------------------------------------
// prep: hoist all state-linear terms.
//  sfd[i][b][ch] = fir_state.w0 + fir_state.w1 + sf_b      (zp = sfc*u + sfd)
//  sfc[i][ch]    = sf_w[...,2]
//  mixer uniformized: y = (mix1[c]*x1*v + mix0[b][c]) * x2
//   HCS: mix0 = sum(state*h[0:6]) + D      mix1 = h[6]
//   HCM: mix0 = sum_k state[k]*h[127-k]    mix1 = h[0] + D
//   HCL: mix0 = sum res*exp(lp)*iir        mix1 = sum(res) + D
// ---------------------------------------------------------------------------
__global__ __launch_bounds__(256) void prep_kernel(
    const float* __restrict__ sf_w, const float* __restrict__ sf_b,
    const float* __restrict__ fir_state,
    const float* __restrict__ hcs_h, const float* __restrict__ hcs_D, const float* __restrict__ hcs_state,
    const float* __restrict__ hcm_h, const float* __restrict__ hcm_D, const float* __restrict__ hcm_state,
    const float* __restrict__ lp, const float* __restrict__ resd, const float* __restrict__ hcl_D,
    const float* __restrict__ iir,
    unsigned long long kbits,
    float* __restrict__ sfd, float* __restrict__ sfc,
    float* __restrict__ mix0, float* __restrict__ mix1)
{
  int blk = blockIdx.x, tid = threadIdx.x;
  if (blk < 768) {
    int idx = blk * 256 + tid;                 // over 32*2*3072
    int i = idx / (BATCH * H3);
    int r = idx % (BATCH * H3);
    int b = r / H3, ch = r % H3;
    const float* fs = fir_state + ((size_t)(i * BATCH + b) * H3 + ch) * 2;
    const float* sw = sf_w + ((size_t)i * H3 + ch) * 3;
    sfd[idx] = fs[0] * sw[0] + fs[1] * sw[1] + sf_b[i * H3 + ch];
    if (b == 0) sfc[i * H3 + ch] = sw[2];
  } else if (blk < 1024) {
    int idx = (blk - 768) * 256 + tid;         // over 32*2*1024
    int i = idx >> 11;
    int r = idx & 2047;
    int b = r >> 10, c = r & 1023;
    int kind = (int)((kbits >> (2 * i)) & 3ull);
    if (kind == 0) {
      const float* st = hcs_state + ((size_t)(i * BATCH + b) * H + c) * 6;
      const float* hh = hcs_h + ((size_t)i * H + c) * 7;
      float acc = 0.f;
#pragma unroll
      for (int k = 0; k < 6; k++) acc += st[k] * hh[k];
      mix0[idx] = acc + hcs_D[i * H + c];
      if (b == 0) mix1[i * H + c] = hh[6];
    } else if (kind == 2) {
      const float* ii = iir + ((size_t)(i * BATCH + b) * H + c) * 16;
      const float* lpp = lp + ((size_t)i * H + c) * 16;
      const float* rs = resd + ((size_t)i * H + c) * 16;
      float acc = 0.f, rsum = 0.f;
#pragma unroll
      for (int k = 0; k < 16; k++) { float rv = rs[k]; acc += rv * expf(lpp[k]) * ii[k]; rsum += rv; }
      mix0[idx] = acc;
      if (b == 0) mix1[i * H + c] = rsum + hcl_D[i * H + c];
    }
    // kind==1 (HCM) handled below (wave per channel); kind==3 nothing
  } else {
    // HCM: one wave per (layer9, b, c); taps over lanes for coalescing
    int w = tid >> 6, lane = tid & 63;
    int widx = (blk - 1024) * 4 + w;
    if (widx < 9 * BATCH * H) {
      int li = widx >> 11;
      int r = widx & 2047;
      int b = r >> 10, c = r & 1023;
      int i = (li >> 1) * 7 + ((li & 1) ? 5 : 1);  // HCM layer ids 1,5,8,12,15,19,22,26,29
      const float* st = hcm_state + ((size_t)(i * BATCH + b) * H + c) * 127;
      const float* hh = hcm_h + ((size_t)i * H + c) * 128;
      float acc = 0.f;
      int k = lane;
      if (k < 127) acc += st[k] * hh[127 - k];
      k = lane + 64;
      if (k < 127) acc += st[k] * hh[127 - k];
      acc = wredSum(acc);
      if (lane == 0) {
        mix0[(i * BATCH + b) * H + c] = acc;
        if (b == 0) mix1[i * H + c] = hh[0] + hcm_D[i * H + c];
      }
    }
  }
}

// ---------------------------------------------------------------------------
// fused rmsnorm + GEMV: out[b,r] = act( scale_b * (W[r,:] . (x_b*nw)) + bias )
// block = 256 threads = 4 waves, 2 rows per wave, 8 rows/block.
// Weight loads issued BEFORE the norm phase so HBM pipe fills immediately.
// ---------------------------------------------------------------------------
template<int ROWS, bool GELU, bool HASBIAS>
__global__ __launch_bounds__(256) void gemv_norm_kernel(
    const float* __restrict__ x, const float* __restrict__ nw,
    const float* __restrict__ W, const float* __restrict__ bias,
    float* __restrict__ out)
{
  __shared__ alignas(16) float xe[BATCH][H];
  __shared__ float red[8];
  __shared__ float scl[BATCH];
  int tid = threadIdx.x, lane = tid & 63, w = tid >> 6;
  int r0 = blockIdx.x * 8 + w * 2;
  const float4* row0 = (const float4*)(W + (size_t)r0 * H);
  const float4* row1 = (const float4*)(W + (size_t)(r0 + 1) * H);
  float4 wa[4], wb[4];
#pragma unroll
  for (int j = 0; j < 4; j++) { wa[j] = row0[lane + 64 * j]; wb[j] = row1[lane + 64 * j]; }

  float ss0 = 0.f, ss1 = 0.f;
#pragma unroll
  for (int it = 0; it < 8; it++) {
    int e = tid + it * 256;
    int b = e >> 10, c = e & 1023;
    float xv = x[b * H + c];
    xe[b][c] = xv * nw[c];
    if (it < 4) ss0 += xv * xv; else ss1 += xv * xv;
  }
  ss0 = wredSum(ss0); ss1 = wredSum(ss1);
  if (lane == 0) { red[w] = ss0; red[4 + w] = ss1; }
  __syncthreads();
  if (tid == 0) {
    scl[0] = rsqrtf((red[0] + red[1] + red[2] + red[3]) * (1.0f / H) + EPSF);
    scl[1] = rsqrtf((red[4] + red[5] + red[6] + red[7]) * (1.0f / H) + EPSF);
  }
  __syncthreads();

  float a00 = 0.f, a01 = 0.f, a10 = 0.f, a11 = 0.f;
  const float4* x0 = (const float4*)xe[0];
  const float4* x1 = (const float4*)xe[1];
#pragma unroll
  for (int j = 0; j < 4; j++) {
    float4 h0 = x0[lane + 64 * j], h1 = x1[lane + 64 * j];
    a00 += wa[j].x * h0.x + wa[j].y * h0.y + wa[j].z * h0.z + wa[j].w * h0.w;
    a01 += wa[j].x * h1.x + wa[j].y * h1.y + wa[j].z * h1.z + wa[j].w * h1.w;
    a10 += wb[j].x * h0.x + wb[j].y * h0.y + wb[j].z * h0.z + wb[j].w * h0.w;
    a11 += wb[j].x * h1.x + wb[j].y * h1.y + wb[j].z * h1.z + wb[j].w * h1.w;
  }
  a00 = wredSum(a00); a01 = wredSum(a01); a10 = wredSum(a10); a11 = wredSum(a11);
  if (lane == 0) {
    float s0 = scl[0], s1 = scl[1];
    float b0 = HASBIAS ? bias[r0] : 0.f;
    float b1 = HASBIAS ? bias[r0 + 1] : 0.f;
    float v00 = a00 * s0 + b0, v01 = a01 * s1 + b0;
    float v10 = a10 * s0 + b1, v11 = a11 * s1 + b1;
    if (GELU) { v00 = gelu_t(v00); v01 = gelu_t(v01); v10 = gelu_t(v10); v11 = gelu_t(v11); }
    out[0 * ROWS + r0] = v00;
    out[1 * ROWS + r0] = v01;
    out[0 * ROWS + r0 + 1] = v10;
    out[1 * ROWS + r0 + 1] = v11;
  }
}

// ---------------------------------------------------------------------------
// mixer (redundant per block, L2-broadcast inputs) + out_W GEMV + residual
// kind<3: y = (mix1*x1*v + mix0) * x2 from zp = sfc*z + sfd
// kind==3: combine flash-decode partials into ctx
// ---------------------------------------------------------------------------
__global__ __launch_bounds__(256) void mix_out_kernel(
    int kind,
    const float* __restrict__ z, const float* __restrict__ sfdL, const float* __restrict__ sfcL,
    const float* __restrict__ mix0L, const float* __restrict__ mix1L,
    const float* __restrict__ attP,
    const float* __restrict__ oW, const float* __restrict__ ob,
    const float* __restrict__ x_in, float* __restrict__ x_out)
{
  __shared__ alignas(16) float y[BATCH][H];
  int tid = threadIdx.x, lane = tid & 63, w = tid >> 6;
  int r0 = blockIdx.x * 8 + w * 2;
  const float4* row0 = (const float4*)(oW + (size_t)r0 * H);
  const float4* row1 = (const float4*)(oW + (size_t)(r0 + 1) * H);
  float4 wa[4], wb[4];
#pragma unroll
  for (int j = 0; j < 4; j++) { wa[j] = row0[lane + 64 * j]; wb[j] = row1[lane + 64 * j]; }

  if (kind < 3) {
#pragma unroll
    for (int it = 0; it < 8; it++) {
      int e = tid + it * 256;
      int b = e >> 10, c = e & 1023;
      int n = c >> 6, d = c & 63;
      int base = n * 192 + d;
      float x2 = sfcL[base] * z[b * H3 + base] + sfdL[b * H3 + base];
      float x1 = sfcL[base + 64] * z[b * H3 + base + 64] + sfdL[b * H3 + base + 64];
      float vv = sfcL[base + 128] * z[b * H3 + base + 128] + sfdL[b * H3 + base + 128];
      float t = x1 * vv;
      y[b][c] = (mix1L[c] * t + mix0L[b * H + c]) * x2;
    }
  } else {
#pragma unroll
    for (int it = 0; it < 8; it++) {
      int e = tid + it * 256;
      int b = e >> 10, c = e & 1023;
      int n = c >> 6, d = c & 63;
      float M = -1e30f;
#pragma unroll
      for (int sp = 0; sp < 8; sp++) M = fmaxf(M, attP[((sp * BATCH + b) * NHEADS + n) * 66 + 64]);
      float Ls = 0.f, num = 0.f;
#pragma unroll
      for (int sp = 0; sp < 8; sp++) {
        const float* P = attP + ((sp * BATCH + b) * NHEADS + n) * 66;
        float wgt = expf(P[64] - M);
        Ls += wgt * P[65];
        num += wgt * P[d];
      }
      y[b][c] = num / Ls;
    }
  }
  __syncthreads();

  float a00 = 0.f, a01 = 0.f, a10 = 0.f, a11 = 0.f;
  const float4* y0 = (const float4*)y[0];
  const float4* y1 = (const float4*)y[1];
#pragma unroll
  for (int j = 0; j < 4; j++) {
    float4 h0 = y0[lane + 64 * j], h1 = y1[lane + 64 * j];
    a00 += wa[j].x * h0.x + wa[j].y * h0.y + wa[j].z * h0.z + wa[j].w * h0.w;
    a01 += wa[j].x * h1.x + wa[j].y * h1.y + wa[j].z * h1.z + wa[j].w * h1.w;
    a10 += wb[j].x * h0.x + wb[j].y * h0.y + wb[j].z * h0.z + wb[j].w * h0.w;
    a11 += wb[j].x * h1.x + wb[j].y * h1.y + wb[j].z * h1.z + wb[j].w * h1.w;
  }
  a00 = wredSum(a00); a01 = wredSum(a01); a10 = wredSum(a10); a11 = wredSum(a11);
  if (lane == 0) {
    x_out[0 * H + r0]     = a00 + ob[r0]     + x_in[0 * H + r0];
    x_out[1 * H + r0]     = a01 + ob[r0]     + x_in[1 * H + r0];
    x_out[0 * H + r0 + 1] = a10 + ob[r0 + 1] + x_in[0 * H + r0 + 1];
    x_out[1 * H + r0 + 1] = a11 + ob[r0 + 1] + x_in[1 * H + r0 + 1];
  }
}

// ---------------------------------------------------------------------------
// W2 GEMV + residual (rows of length FF=2048), h staged in LDS
// ---------------------------------------------------------------------------
__global__ __launch_bounds__(256) void gemv_mlp2_kernel(
    const float* __restrict__ h, const float* __restrict__ W2,
    const float* __restrict__ x_in, float* __restrict__ x_out)
{
  __shared__ alignas(16) float hs[BATCH][FF];
  int tid = threadIdx.x, lane = tid & 63, w = tid >> 6;
  int r = blockIdx.x * 4 + w;
  const float4* row = (const float4*)(W2 + (size_t)r * FF);
  float4 wv[8];
#pragma unroll
  for (int j = 0; j < 8; j++) wv[j] = row[lane + 64 * j];
#pragma unroll
  for (int it = 0; it < 16; it++) {
    int e = tid + it * 256;
    int b = e >> 11, c = e & 2047;
    hs[b][c] = h[b * FF + c];
  }
  __syncthreads();
  float a0 = 0.f, a1 = 0.f;
  const float4* h0 = (const float4*)hs[0];
  const float4* h1 = (const float4*)hs[1];
#pragma unroll
  for (int j = 0; j < 8; j++) {
    float4 p = h0[lane + 64 * j], q = h1[lane + 64 * j];
    a0 += wv[j].x * p.x + wv[j].y * p.y + wv[j].z * p.z + wv[j].w * p.w;
    a1 += wv[j].x * q.x + wv[j].y * q.y + wv[j].z * q.z + wv[j].w * q.w;
  }
  a0 = wredSum(a0); a1 = wredSum(a1);
  if (lane == 0) {
    x_out[0 * H + r] = a0 + x_in[0 * H + r];
    x_out[1 * H + r] = a1 + x_in[1 * H + r];
  }
}

// ---------------------------------------------------------------------------
// flash-decode attention partials: grid = (8 splits x 16 heads x 2 batch)
// split chunk = 256 positions; rope applied to q,k from z; new k/v at s==pos
// ---------------------------------------------------------------------------
__global__ __launch_bounds__(256) void attn_kernel(
    const float* __restrict__ z, const int* __restrict__ posp,
    const float* __restrict__ kc, const float* __restrict__ vc,
    const float* __restrict__ cosT, const float* __restrict__ sinT,
    float* __restrict__ P)
{
  int sp = blockIdx.x & 7, n = (blockIdx.x >> 3) & 15, b = blockIdx.x >> 7;
  int pos = *posp;
  __shared__ alignas(16) float q_s[HDIM], k_s[HDIM], v_s[HDIM];
  __shared__ float eg[256];
  __shared__ float redA[4];
  __shared__ alignas(16) float osum[4][HDIM];
  int tid = threadIdx.x, lane = tid & 63, w = tid >> 6;

  if (tid < 64) {
    int d = tid, j = d & 31;
    float cs = cosT[pos * 32 + j], sn = sinT[pos * 32 + j];
    float qv = z[b * H3 + n * 64 + d];
    float qo = z[b * H3 + n * 64 + ((d + 32) & 63)];
    q_s[d] = ((d < 32) ? (qv * cs - qo * sn) : (qv * cs + qo * sn)) * 0.125f;
    float kv = z[b * H3 + 1024 + n * 64 + d];
    float ko = z[b * H3 + 1024 + n * 64 + ((d + 32) & 63)];
    k_s[d] = (d < 32) ? (kv * cs - ko * sn) : (kv * cs + ko * sn);
    v_s[d] = z[b * H3 + 2048 + n * 64 + d];
  }
  __syncthreads();

  int s = sp * 256 + tid;
  float logit = -1e30f;
  if (s <= pos) {
    const float4* k4 = (s == pos) ? (const float4*)k_s
                                  : (const float4*)(kc + (((size_t)b * SEQ + s) * NHEADS + n) * HDIM);
    const float4* q4 = (const float4*)q_s;
    float acc = 0.f;
#pragma unroll
    for (int j = 0; j < 16; j++) {
      float4 kk = k4[j], qq = q4[j];
      acc += kk.x * qq.x + kk.y * qq.y + kk.z * qq.z + kk.w * qq.w;
    }
    logit = acc;
  }
  float m = wredMax(logit);
  if (lane == 0) redA[w] = m;
  __syncthreads();
  m = fmaxf(fmaxf(redA[0], redA[1]), fmaxf(redA[2], redA[3]));
  float e = (s <= pos) ? expf(logit - m) : 0.f;
  eg[tid] = e;
  float ps = wredSum(e);
  __syncthreads();
  if (lane == 0) redA[w] = ps;
  __syncthreads();
  float lsum = redA[0] + redA[1] + redA[2] + redA[3];

  // PV: wave w covers local positions [w*64, w*64+64); lane = 16 dims x 4 rows
  int dgrp = lane & 15, srow = lane >> 4;
  float4 acc = make_float4(0.f, 0.f, 0.f, 0.f);
#pragma unroll 4
  for (int it = 0; it < 16; it++) {
    int sl = w * 64 + it * 4;
    if (sp * 256 + sl > pos) break;              // uniform within wave
    int sli = sl + srow;
    int ss = sp * 256 + sli;
    float ev = eg[sli];                           // 0 for ss>pos
    const float4* v4 = (ss == pos) ? (const float4*)v_s
                                   : (const float4*)(vc + (((size_t)b * SEQ + ss) * NHEADS + n) * HDIM);
    float4 vv = v4[dgrp];
    acc.x += ev * vv.x; acc.y += ev * vv.y; acc.z += ev * vv.z; acc.w += ev * vv.w;
  }
#pragma unroll
  for (int mm = 16; mm <= 32; mm <<= 1) {
    acc.x += __shfl_xor(acc.x, mm, 64);
    acc.y += __shfl_xor(acc.y, mm, 64);
    acc.z += __shfl_xor(acc.z, mm, 64);
    acc.w += __shfl_xor(acc.w, mm, 64);
  }
  if (srow == 0) ((float4*)osum[w])[dgrp] = acc;
  __syncthreads();
  float* Pp = P + ((size_t)(sp * BATCH + b) * NHEADS + n) * 66;
  if (tid < 64) Pp[tid] = osum[0][tid] + osum[1][tid] + osum[2][tid] + osum[3][tid];
  if (tid == 64) Pp[64] = m;
  if (tid == 65) Pp[65] = lsum;
}

// ---------------------------------------------------------------------------
extern "C" void kernel_launch(void* const* d_in, const int* in_sizes, int n_in,
                              void* d_out, int out_size, void* d_ws, size_t ws_size,
                              hipStream_t stream) {
  (void)in_sizes; (void)n_in; (void)out_size; (void)ws_size;
  const float* x0    = (const float*)d_in[0];
  const int*   posp  = (const int*)d_in[1];
  const float* n1    = (const float*)d_in[2];
  const float* n2    = (const float*)d_in[3];
  const float* pW    = (const float*)d_in[4];
  const float* pb    = (const float*)d_in[5];
  const float* oW    = (const float*)d_in[6];
  const float* ob    = (const float*)d_in[7];
  const float* W1    = (const float*)d_in[8];
  const float* W2    = (const float*)d_in[9];
  const float* sfw   = (const float*)d_in[10];
  const float* sfb   = (const float*)d_in[11];
  const float* hcs_h = (const float*)d_in[12];
  const float* hcs_D = (const float*)d_in[13];
  const float* hcm_h = (const float*)d_in[14];
  const float* hcm_D = (const float*)d_in[15];
  const float* lp    = (const float*)d_in[16];
  const float* resd  = (const float*)d_in[17];
  const float* hclD  = (const float*)d_in[18];
  const float* fir   = (const float*)d_in[19];
  const float* hcsS  = (const float*)d_in[20];
  const float* hcmS  = (const float*)d_in[21];
  const float* iir   = (const float*)d_in[22];
  const float* kc    = (const float*)d_in[23];
  const float* vc    = (const float*)d_in[24];
  const float* cosT  = (const float*)d_in[25];
  const float* sinT  = (const float*)d_in[26];

  float* ws    = (float*)d_ws;
  float* xbuf0 = ws;                 // 2048
  float* xbuf1 = ws + 2048;          // 2048
  float* zbuf  = ws + 4096;          // 6144
  float* hbuf  = ws + 10240;         // 4096
  float* attP  = ws + 14336;         // 16896
  float* sfd   = ws + 31232;         // 196608
  float* sfc   = ws + 227840;        // 98304
  float* mix0  = ws + 326144;        // 65536
  float* mix1  = ws + 391680;        // 32768

  static const int KIND[LAYERS] = {0,1,2,3,0,1,2,0,1,2,3,0,1,2,0,1,2,3,0,1,2,0,1,2,3,0,1,2,0,1,2,3};
  unsigned long long kbits = 0ull;
  for (int i = 0; i < LAYERS; i++) kbits |= ((unsigned long long)KIND[i]) << (2 * i);

  prep_kernel<<<5632, 256, 0, stream>>>(sfw, sfb, fir, hcs_h, hcs_D, hcsS,
      hcm_h, hcm_D, hcmS, lp, resd, hclD, iir, kbits, sfd, sfc, mix0, mix1);

  const float* xsrc = x0;
  int att = 0;
  for (int i = 0; i < LAYERS; i++) {
    gemv_norm_kernel<H3, false, true><<<H3 / 8, 256, 0, stream>>>(
        xsrc, n1 + i * H, pW + (size_t)i * H3 * H, pb + i * H3, zbuf);
    if (KIND[i] == 3) {
      attn_kernel<<<256, 256, 0, stream>>>(
          zbuf, posp, kc + (size_t)att * BATCH * SEQ * NHEADS * HDIM,
          vc + (size_t)att * BATCH * SEQ * NHEADS * HDIM, cosT, sinT, attP);
      att++;
    }
    mix_out_kernel<<<H / 8, 256, 0, stream>>>(
        KIND[i], zbuf, sfd + (size_t)i * BATCH * H3, sfc + (size_t)i * H3,
        mix0 + (size_t)i * BATCH * H, mix1 + (size_t)i * H, attP,
        oW + (size_t)i * H * H, ob + i * H, xsrc, xbuf1);
    gemv_norm_kernel<FF, true, false><<<FF / 8, 256, 0, stream>>>(
        xbuf1, n2 + i * H, W1 + (size_t)i * FF * H, nullptr, hbuf);
    gemv_mlp2_kernel<<<H / 4, 256, 0, stream>>>(
        hbuf, W2 + (size_t)i * H * FF, xbuf1, (i == 31) ? (float*)d_out : xbuf0);
    xsrc = xbuf0;
  }
}